// Round 1
// baseline (206.008 us; speedup 1.0000x reference)
//
#include <hip/hip_runtime.h>

using short8  = __attribute__((ext_vector_type(8))) short;
using floatx4 = __attribute__((ext_vector_type(4))) float;

constexpr int D   = 4096;
constexpr int Q   = 16;
constexpr int L   = 24;
constexpr int C   = 512;
constexpr int RB  = 16;              // rows per block = one MFMA M-tile
constexpr int NW  = 8;               // waves per block
constexpr int BK  = 256;             // k per staged chunk
constexpr int NCH = D / BK;          // 16 chunks
constexpr float PI_F = 3.14159265358979323846f;

// fp32 -> bf16 hi/lo by truncation (unchanged from passing kernel).
__device__ inline void cvt8(const float4& v0, const float4& v1,
                            short8& hi, short8& lo) {
    const float f[8] = {v0.x, v0.y, v0.z, v0.w, v1.x, v1.y, v1.z, v1.w};
    #pragma unroll
    for (int j = 0; j < 8; ++j) {
        union { float f; unsigned u; } a, b, c;
        a.f = f[j];
        hi[j] = (short)(a.u >> 16);
        b.u = a.u & 0xFFFF0000u;
        c.f = a.f - b.f;
        lo[j] = (short)(c.u >> 16);
    }
}

// 16-byte global -> LDS direct copy. Dest is wave-uniform base; HW adds lane*16.
__device__ inline void gll16(const void* g, void* l) {
    __builtin_amdgcn_global_load_lds(
        (const __attribute__((address_space(1))) void*)g,
        (__attribute__((address_space(3))) void*)l, 16, 0, 0);
}

// K-loop rebuilt as m97-style global_load_lds streaming:
//  - chunk = 16 rows x 256 fp32 of A (feat) and B (pw), double-buffered: 64 KB LDS
//  - each global_load_lds_dwordx4 covers 1 KB CONTIGUOUS of one row (fire-and-forget,
//    32 KB in flight per block vs ~256 B/wave before -> covers HBM latency, page-friendly)
//  - both-sides XOR swizzle: source byte (lane*16)^((row&7)<<4), read byte (col)^((row&7)<<4)
//    -> ds_read_b128 fragment reads bank-conflict-free (each 8-lane group spans all 32 banks)
//  - one __syncthreads per chunk; its vmcnt(0) drain IS the stage(c) wait; stage(c+1)
//    issued right after the barrier overlaps compute(c) (disjoint buffer, prev readers done)
//  - s_red / trig / qubits aliased into the staging LDS (trig computed post-loop)
//    so the block stays at exactly 64 KB -> 2 blocks/CU
__global__ __launch_bounds__(512, 4)
void vqc_fused(const float* __restrict__ feat,
               const float* __restrict__ pw,
               const float* __restrict__ pb,
               const float* __restrict__ vw,
               const float* __restrict__ lw,
               const float* __restrict__ lb,
               float* __restrict__ out, int B)
{
    // A0 @0..4096, A1 @4096..8192, B0 @8192..12288, B1 @12288..16384 (floats)
    // aliases after K-loop: s_red[8][16][16] @0, s_trig[384*6] @2048, s_qub[16][16] @4352
    __shared__ __align__(16) float lds[16384];   // 64 KB

    const int t    = threadIdx.x;
    const int wave = t >> 6;
    const int lane = t & 63;
    const int row0 = blockIdx.x * RB;
    const int mrow = lane & 15;          // A row (feat) / B row (q)
    const int quad = lane >> 4;

    const int r_a = wave * 2;            // this wave stages rows r_a, r_a+1 (A and B)

    floatx4 acc = {0.f, 0.f, 0.f, 0.f};

    auto stage = [&](int c, int b) {
        #pragma unroll
        for (int i = 0; i < 2; ++i) {
            const int r   = r_a + i;                       // uniform within wave
            const int off = (lane * 16) ^ ((r & 7) << 4);  // pre-swizzled source
            int rr = row0 + r; if (rr >= B) rr = B - 1;    // clamp; stores guarded
            const char* ga = (const char*)(feat + (size_t)rr * D + (size_t)c * BK) + off;
            const char* gb = (const char*)(pw   + (size_t)r  * D + (size_t)c * BK) + off;
            gll16(ga, (void*)&lds[(size_t)b * 4096 + r * BK]);
            gll16(gb, (void*)&lds[8192 + (size_t)b * 4096 + r * BK]);
        }
    };

    stage(0, 0);

    const int sw = (mrow & 7) << 4;                 // read-side swizzle
    const int cb = (wave * 32 + quad * 8) * 4;      // byte col of this lane's 8-float frag
    for (int c = 0; c < NCH; ++c) {
        __syncthreads();                 // vmcnt(0) drain: stage(c) complete; all waves
                                         // past compute(c-1) -> buf[(c+1)&1] is free
        if (c + 1 < NCH) stage(c + 1, (c + 1) & 1);   // overlaps compute(c)

        const char* arow = (const char*)&lds[(size_t)(c & 1) * 4096 + mrow * BK];
        const char* brow = (const char*)&lds[8192 + (size_t)(c & 1) * 4096 + mrow * BK];
        const float4 a0 = *(const float4*)(arow + ((cb     ) ^ sw));
        const float4 a1 = *(const float4*)(arow + ((cb + 16) ^ sw));
        const float4 b0 = *(const float4*)(brow + ((cb     ) ^ sw));
        const float4 b1 = *(const float4*)(brow + ((cb + 16) ^ sw));
        short8 ah, al, bh, bl;
        cvt8(a0, a1, ah, al);
        cvt8(b0, b1, bh, bl);
        acc = __builtin_amdgcn_mfma_f32_16x16x32_bf16(al, bh, acc, 0, 0, 0);
        acc = __builtin_amdgcn_mfma_f32_16x16x32_bf16(ah, bl, acc, 0, 0, 0);
        acc = __builtin_amdgcn_mfma_f32_16x16x32_bf16(ah, bh, acc, 0, 0, 0);
    }

    // ---- wave partials -> s_red (aliases A0 head; A0 last read at chunk 14) ----
    // C/D layout: col (=q) = lane&15, row (=m) = quad*4 + reg  (unchanged)
    float* s_red = lds;                  // [NW][RB][Q]
    #pragma unroll
    for (int i = 0; i < 4; ++i)
        s_red[(wave * RB + quad * 4 + i) * Q + mrow] = acc[i];
    __syncthreads();

    // ---- trig table (post-loop: region aliases A0 tail / A1 head, now dead) ----
    float* s_trig = lds + 2048;          // [L*Q][6]
    if (t < L * Q) {
        const float phi = vw[t * 3 + 0], th = vw[t * 3 + 1], om = vw[t * 3 + 2];
        float* tr = s_trig + t * 6;
        tr[0] = cosf(phi); tr[1] = sinf(phi);
        tr[2] = cosf(th);  tr[3] = sinf(th);
        tr[4] = cosf(om);  tr[5] = sinf(om);
    }
    __syncthreads();

    // ---- VQC: one thread per (row, q), fp32 ----
    float* s_qub = lds + 2048 + L * Q * 6;   // @4352, [RB][Q]
    if (t < RB * Q) {
        const int r = t >> 4, q = t & 15;
        float p = 0.f;
        #pragma unroll
        for (int w = 0; w < NW; ++w) p += s_red[(w * RB + r) * Q + q];
        p += pb[q];
        const float angle = PI_F * tanhf(p);
        float x = sinf(angle), y = 0.f, z = cosf(angle);
        #pragma unroll
        for (int l = 0; l < L; ++l) {
            const float* w6 = s_trig + (l * 16 + q) * 6;
            const float cp = w6[0], sp = w6[1];
            const float ct = w6[2], st = w6[3];
            const float co = w6[4], so = w6[5];
            const float x1 = x * cp - y * sp;
            const float y1 = x * sp + y * cp;
            const float x2 = x1 * ct + z * st;
            const float z2 = -x1 * st + z * ct;
            x = x2 * co - y1 * so;
            y = x2 * so + y1 * co;
            z = z2;
        }
        s_qub[r * Q + q] = z;
    }
    __syncthreads();

    // ---- epilogue: out[RB][512] = qubits[RB][16] @ lw[16][512] + lb ----
    {
        const int cidx = t;              // 512 threads -> one output column each
        float wv[Q];
        #pragma unroll
        for (int q = 0; q < Q; ++q) wv[q] = lw[(size_t)q * C + cidx];
        const float lbv = lb[cidx];
        #pragma unroll 4
        for (int r = 0; r < RB; ++r) {
            if (row0 + r >= B) break;
            float a2 = lbv;
            #pragma unroll
            for (int q = 0; q < Q; ++q) a2 = fmaf(s_qub[r * Q + q], wv[q], a2);
            out[(size_t)(row0 + r) * C + cidx] = a2;
        }
    }
}

extern "C" void kernel_launch(void* const* d_in, const int* in_sizes, int n_in,
                              void* d_out, int out_size, void* d_ws, size_t ws_size,
                              hipStream_t stream) {
    // Size-keyed input mapping (permutation-proof; falls back to dict order).
    const float *feat = nullptr, *pw = nullptr, *pb = nullptr,
                *vw = nullptr, *lw = nullptr, *lb = nullptr;
    long long B = 0;
    bool ok = false;
    if (n_in == 6) {
        int imax = 0;
        for (int i = 1; i < 6; ++i)
            if ((long long)in_sizes[i] > (long long)in_sizes[imax]) imax = i;
        const long long scales[2] = {1, 4};
        for (int s = 0; s < 2 && !ok; ++s) {
            const long long sc = scales[s];
            int m[6] = {imax, -1, -1, -1, -1, -1};
            bool good = ((long long)in_sizes[imax] % (sc * D)) == 0;
            for (int i = 0; i < 6 && good; ++i) {
                if (i == imax) continue;
                long long e = (long long)in_sizes[i];
                if (e % sc) { good = false; break; }
                e /= sc;
                if      (e == 65536 && m[1] < 0) m[1] = i;
                else if (e == 16    && m[2] < 0) m[2] = i;
                else if (e == 1152  && m[3] < 0) m[3] = i;
                else if (e == 8192  && m[4] < 0) m[4] = i;
                else if (e == 512   && m[5] < 0) m[5] = i;
                else good = false;
            }
            if (good && m[1] >= 0 && m[2] >= 0 && m[3] >= 0 && m[4] >= 0 && m[5] >= 0) {
                feat = (const float*)d_in[m[0]];
                pw   = (const float*)d_in[m[1]];
                pb   = (const float*)d_in[m[2]];
                vw   = (const float*)d_in[m[3]];
                lw   = (const float*)d_in[m[4]];
                lb   = (const float*)d_in[m[5]];
                B = (long long)in_sizes[imax] / (sc * D);
                ok = true;
            }
        }
    }
    if (!ok) {   // fallback: setup_inputs dict order, element counts
        feat = (const float*)d_in[0];
        pw   = (const float*)d_in[1];
        pb   = (const float*)d_in[2];
        vw   = (const float*)d_in[3];
        lw   = (const float*)d_in[4];
        lb   = (const float*)d_in[5];
        B = in_sizes[0] / D;
    }
    float* out = (float*)d_out;

    const int nblocks = (int)((B + RB - 1) / RB);
    dim3 grid(nblocks), block(512);
    hipLaunchKernelGGL(vqc_fused, grid, block, 0, stream,
                       feat, pw, pb, vw, lw, lb, out, (int)B);
}